// Round 5
// baseline (3670.009 us; speedup 1.0000x reference)
//
#include <hip/hip_runtime.h>

typedef __attribute__((ext_vector_type(8))) short short8;
typedef __attribute__((ext_vector_type(4))) float fvec4;

#define NW 64
#define NN 144
#define CC 192
#define NH 6
#define LL 32
#define NLON 15
#define TT (NLON*NW*NN)   // 138240

__device__ __forceinline__ float bf2f(ushort v) {
  union { unsigned int u; float f; } x;
  x.u = ((unsigned int)v) << 16;
  return x.f;
}
__device__ __forceinline__ ushort f2bf(float f) {
  union { float f; unsigned int u; } x; x.f = f;
  unsigned int r = (x.u + 0x7FFFu + ((x.u >> 16) & 1u)) >> 16;
  return (ushort)r;
}

// Robust dtype detector (correct for both worlds; returns f32 for this problem).
__device__ bool arr_is_f32(const void* p) {
  const ushort* u = (const ushort*)p;
  int sane = 0;
#pragma unroll
  for (int k = 0; k < 16; ++k) {
    float v = bf2f(u[k * 514]);
    if (__builtin_fabsf(v) < 64.f) ++sane;
  }
  return sane < 16;
}
__device__ __forceinline__ float loadS(const void* p, size_t i, bool f) {
  return f ? ((const float*)p)[i] : bf2f(((const ushort*)p)[i]);
}

// ---------------------------------------------------------------------------
// Pure-VALU fused QKV + attention for one (b,h,w) window. 576 thr = 9 waves.
// LDS union M: phase 1 = W^T slice as bf16; phase 2 = q,k,v f32, stride 36.
__global__ __launch_bounds__(576) void attn_valu(const void* __restrict__ x,
                                                 const void* __restrict__ qkv_w,
                                                 const void* __restrict__ qkv_b,
                                                 const void* __restrict__ mask,
                                                 const void* __restrict__ bt,
                                                 float* __restrict__ out) {
  __shared__ float M[15552];          // 62,208 B
  ushort* WT = (ushort*)M;            // phase 1: WT[k*96 + r], r = which*32 + l
  const bool xf = arr_is_f32(x);
  const bool wf = arr_is_f32(qkv_w);  // qkv_b shares policy
  const bool bf = arr_is_f32(bt);
  const int w = blockIdx.x, h = blockIdx.y, b = blockIdx.z;
  const int tid = threadIdx.x;

  // stage W^T slice for this head
  for (int idx = tid; idx < 96 * 192; idx += 576) {
    int r = idx / 192, k = idx - r * 192;
    int grow = (r >> 5) * 192 + h * 32 + (r & 31);   // q rows, k rows(+192), v rows(+384)
    WT[k * 96 + r] = f2bf(loadS(qkv_w, (size_t)grow * 192 + k, wf));
  }
  __syncthreads();

  const int n = tid >> 2, g = tid & 3;   // n = token row, g = quarter
  const size_t tok0 = ((size_t)b * NW + w) * NN;

  // ---- phase 1: qkv = x @ W^T + b  (thread: channels g*24 .. g*24+23 of row n)
  float acc[24];
#pragma unroll
  for (int j = 0; j < 24; ++j) acc[j] = 0.f;
  {
    const size_t xb = (tok0 + n) * (size_t)CC;
    for (int k = 0; k < 192; ++k) {
      float xv = loadS(x, xb + k, xf);
      const short8* wp = (const short8*)(WT + k * 96 + g * 24);
      short8 w0 = wp[0], w1 = wp[1], w2 = wp[2];
#pragma unroll
      for (int j = 0; j < 8; ++j) {
        acc[j]      += xv * bf2f((ushort)w0[j]);
        acc[8 + j]  += xv * bf2f((ushort)w1[j]);
        acc[16 + j] += xv * bf2f((ushort)w2[j]);
      }
    }
  }
  __syncthreads();   // all waves done reading WT — safe to overwrite with q,k,v
#pragma unroll
  for (int j = 0; j < 24; ++j) {
    int r = g * 24 + j, which = r >> 5, l = r & 31;
    M[which * 5184 + n * 36 + l] = acc[j] + loadS(qkv_b, which * 192 + h * 32 + l, wf);
  }
  __syncthreads();

  // ---- phase 2: online-softmax attention. Thread owns row n, dims g*8..g*8+7.
  const float* qL = M;
  const float* kL = M + 5184;
  const float* vL = M + 10368;
  fvec4 q0 = *(const fvec4*)(qL + n * 36 + g * 8);
  fvec4 q1 = *(const fvec4*)(qL + n * 36 + g * 8 + 4);
  int z1 = n / 72, r1 = n - z1 * 72;
  int h1 = r1 / 12, w1 = r1 - h1 * 12;
  const size_t mb = (((size_t)b * NW + w) * NN + n) * NN;
  const float scale = 0.17677669529663687f;   // 1/sqrt(32)
  float mx = -1e30f, sum = 0.f;
  fvec4 a0 = {0, 0, 0, 0}, a1 = {0, 0, 0, 0};
  for (int m = 0; m < 144; ++m) {
    fvec4 k0 = *(const fvec4*)(kL + m * 36 + g * 8);
    fvec4 k1 = *(const fvec4*)(kL + m * 36 + g * 8 + 4);
    float p = q0[0]*k0[0] + q0[1]*k0[1] + q0[2]*k0[2] + q0[3]*k0[3]
            + q1[0]*k1[0] + q1[1]*k1[1] + q1[2]*k1[2] + q1[3]*k1[3];
    p += __shfl_xor(p, 1);            // 4 g-threads of row n sum partial dots
    p += __shfl_xor(p, 2);
    int z2 = m / 72, r2 = m - z2 * 72;
    int h2 = r2 / 12, w2 = r2 - h2 * 12;
    int epi = 828 * (z1 + 2 * z2) + 23 * (h1 + 6 * h2) + (w1 - w2 + 11);
    float s = p * scale + loadS(bt, (size_t)epi * 384 + w * 6 + h, bf)
                        + loadS(mask, mb + m, xf);
    float nmx = fmaxf(mx, s);
    float al = __expf(mx - nmx);
    float e  = __expf(s - nmx);
    sum = sum * al + e;
    fvec4 v0 = *(const fvec4*)(vL + m * 36 + g * 8);
    fvec4 v1 = *(const fvec4*)(vL + m * 36 + g * 8 + 4);
#pragma unroll
    for (int i = 0; i < 4; ++i) {
      a0[i] = a0[i] * al + e * v0[i];
      a1[i] = a1[i] * al + e * v1[i];
    }
    mx = nmx;
  }
  float inv = 1.f / sum;
  fvec4 o0, o1;
#pragma unroll
  for (int i = 0; i < 4; ++i) { o0[i] = a0[i] * inv; o1[i] = a1[i] * inv; }
  float* op = out + (tok0 + n) * CC + h * LL + g * 8;   // f32 OUTPUT
  *(fvec4*)op = o0;
  *(fvec4*)(op + 4) = o1;
}

// ---------------------------------------------------------------------------
// Pure-VALU in-place projection on f32 d_out. Block owns 64 rows.
__global__ __launch_bounds__(256) void proj_valu(float* __restrict__ io,
                                                 const void* __restrict__ pw,
                                                 const void* __restrict__ pb) {
  __shared__ ushort A[64 * 192];      // bf16 staged activations
  __shared__ ushort WT[192 * 96];     // half of proj_w, transposed
  const bool pf = arr_is_f32(pw);     // proj_b shares policy
  const int tid = threadIdx.x;
  const size_t m0 = (size_t)blockIdx.x * 64;
  for (int idx = tid; idx < 64 * 192; idx += 256)
    A[idx] = f2bf(io[m0 * CC + idx]);
  const int t = tid >> 2, g = tid & 3;
#pragma unroll
  for (int p = 0; p < 2; ++p) {
    for (int idx = tid; idx < 96 * 192; idx += 256) {
      int r = idx / 192, k = idx - r * 192;
      WT[k * 96 + r] = f2bf(loadS(pw, (size_t)(p * 96 + r) * 192 + k, pf));
    }
    __syncthreads();
    float acc[24];
#pragma unroll
    for (int j = 0; j < 24; ++j) acc[j] = 0.f;
    for (int k = 0; k < 192; ++k) {
      float av = bf2f(A[t * 192 + k]);
      const short8* wp = (const short8*)(WT + k * 96 + g * 24);
      short8 w0 = wp[0], w1 = wp[1], w2 = wp[2];
#pragma unroll
      for (int j = 0; j < 8; ++j) {
        acc[j]      += av * bf2f((ushort)w0[j]);
        acc[8 + j]  += av * bf2f((ushort)w1[j]);
        acc[16 + j] += av * bf2f((ushort)w2[j]);
      }
    }
    fvec4 o[6];
#pragma unroll
    for (int j = 0; j < 24; ++j)
      o[j >> 2][j & 3] = acc[j] + loadS(pb, p * 96 + g * 24 + j, pf);
    __syncthreads();   // all reads of A/WT done before overwrite & restage
#pragma unroll
    for (int q = 0; q < 6; ++q)
      *(fvec4*)(io + (m0 + t) * CC + p * 96 + g * 24 + q * 4) = o[q];
  }
}

// ---------------------------------------------------------------------------
extern "C" void kernel_launch(void* const* d_in, const int* in_sizes, int n_in,
                              void* d_out, int out_size, void* d_ws, size_t ws_size,
                              hipStream_t stream) {
  const void *x = d_in[0], *mask = d_in[1], *qkv_w = d_in[2], *qkv_b = d_in[3],
             *proj_w = d_in[4], *proj_b = d_in[5], *bias_tab = d_in[6];
  for (int i = 0; i < n_in; ++i) {
    switch (in_sizes[i]) {
      case 26542080: x = d_in[i]; break;
      case 19906560: mask = d_in[i]; break;
      case 110592:   qkv_w = d_in[i]; break;
      case 576:      qkv_b = d_in[i]; break;
      case 36864:    proj_w = d_in[i]; break;
      case 192:      proj_b = d_in[i]; break;
      case 1271808:  bias_tab = d_in[i]; break;
      default: break;
    }
  }
  float* out = (float*)d_out;
  attn_valu<<<dim3(NW, NH, NLON), 576, 0, stream>>>(x, qkv_w, qkv_b, mask, bias_tab, out);
  proj_valu<<<TT / 64, 256, 0, stream>>>(out, proj_w, proj_b);
}